// Round 1
// baseline (1872.729 us; speedup 1.0000x reference)
//
#include <hip/hip_runtime.h>
#include <hip/hip_bf16.h>
#include <math.h>
#include <stdint.h>

// ---------------------------------------------------------------------------
// HMQ MLP: fake-quant(int8) GEMM1 + bias + exact GELU -> fake-quant -> GEMM2
// int8 MFMA (mfma_i32_16x16x64_i8), exact int32 accumulation.
// R7: K-loop rewritten from direct-global register ping-pong (R6: MfmaUtil
// 27%, VALUBusy 53%, Occ 20% -> near-serial MFMA/L2/VALU streams) to an
// LDS-staged double-buffer with counted vmcnt (T3/T4-lite):
//   - block 256x256, 8 waves (wave tile stays 64x128 -> epilogue unchanged)
//   - K-step 64: A(16KB)+B(16KB) staged via global_load_lds (1KB/instr,
//     linear dest; int8 staged layout == MFMA fragment layout, so LDS reads
//     are contiguous 1KB ds_read_b128: swizzle-free, conflict-free)
//   - 2-deep prefetch, s_waitcnt vmcnt(4) in steady state (never drain),
//     raw s_barrier, setprio(1) around MFMA cluster
//   - L2 traffic/MFMA: 384 B -> 128 B; regs ~215 -> 2x512thr blocks/CU
// Epilogue LDS transpose aliases the operand buffer (64 KB total).
// ---------------------------------------------------------------------------

typedef int    v4i    __attribute__((ext_vector_type(4)));
typedef short  short8 __attribute__((ext_vector_type(8)));
typedef int8_t char8  __attribute__((ext_vector_type(8)));

#define QMAXF 127.0f

// branch-free GELU: erf via Abramowitz-Stegun 7.1.26, |eps|<2e-7
__device__ __forceinline__ float gelu_exact(float v) {
    float z = fabsf(v) * 0.70710678118654752440f;
    float t = __builtin_amdgcn_rcpf(fmaf(0.3275911f, z, 1.0f));
    float p = fmaf(fmaf(fmaf(fmaf(1.061405429f, t, -1.453152027f), t,
                             1.421413741f), t, -0.284496736f), t,
                   0.254829592f) * t;
    float e = __expf(-z * z);
    float erfz = fmaf(-p, e, 1.0f);
    float erfv = v < 0.f ? -erfz : erfz;
    return 0.5f * v * (1.0f + erfv);
}

// ---------------- init: zero the scale slots ----------------
__global__ void init_slots(unsigned int* slots) {
    if (threadIdx.x < 8) slots[threadIdx.x] = 0u;
}

// ---------------- absmax reduction (fp32, float4) ----------------
__global__ void absmax_kernel(const float4* __restrict__ t, int n4,
                              unsigned int* __restrict__ slot) {
    float m = 0.f;
    int stride = gridDim.x * blockDim.x;
    for (int i = blockIdx.x * blockDim.x + threadIdx.x; i < n4; i += stride) {
        float4 v = t[i];
        m = fmaxf(m, fmaxf(fmaxf(fabsf(v.x), fabsf(v.y)),
                           fmaxf(fabsf(v.z), fabsf(v.w))));
    }
#pragma unroll
    for (int off = 32; off > 0; off >>= 1)
        m = fmaxf(m, __shfl_xor(m, off));
    if ((threadIdx.x & 63) == 0)
        atomicMax(slot, __float_as_uint(m));  // vals >= 0: uint order == float order
}

// ---------------- quantize fp32 -> staged int8, coalesced ----------------
// One wave per 1KB-dest block (16 rows x 64 k). Reads 4x 1KB instrs covering
// 4 full 256B row-segments each (coalesced); transposes via wave-private LDS;
// writes 1KB contiguous.
__global__ void quant_stage_kernel(const float* __restrict__ x, int kshift,
                                   int nblocks, const float* __restrict__ slot,
                                   int8_t* __restrict__ q) {
    __shared__ float qt[4][1088];  // per wave: 16 rows x 68 (pad 4) floats
    const float s = fmaxf(*slot, 1e-8f) / QMAXF;
    const int lane = threadIdx.x & 63;
    const int wv   = threadIdx.x >> 6;
    const int wave0 = (blockIdx.x * blockDim.x + threadIdx.x) >> 6;
    const int nwaves = (gridDim.x * blockDim.x) >> 6;
    const int nkb = 1 << kshift;  // K/64
    const int K = 64 << kshift;
    float* tw = &qt[wv][0];
    for (int wb = wave0; wb < nblocks; wb += nwaves) {
        const int rb = wb >> kshift;
        const int kc = wb & (nkb - 1);
        // coalesced read: instr j covers rows rb*16+j*4..+3, 256B per row
#pragma unroll
        for (int j = 0; j < 4; j++) {
            const int row = rb * 16 + j * 4 + (lane >> 4);
            float4 v = *(const float4*)(x + (size_t)row * K + kc * 64 + (lane & 15) * 4);
            *(float4*)(tw + (j * 4 + (lane >> 4)) * 68 + (lane & 15) * 4) = v;
        }
        // fragment gather: lane -> row15 = lane&15, k-chunk = (lane>>4)*16
        int8_t tmp[16];
#pragma unroll
        for (int t = 0; t < 4; t++) {
            float4 v = *(const float4*)(tw + (lane & 15) * 68 + (lane >> 4) * 16 + t * 4);
            tmp[t*4+0] = (int8_t)fminf(fmaxf(rintf(v.x / s), -127.f), 127.f);
            tmp[t*4+1] = (int8_t)fminf(fmaxf(rintf(v.y / s), -127.f), 127.f);
            tmp[t*4+2] = (int8_t)fminf(fmaxf(rintf(v.z / s), -127.f), 127.f);
            tmp[t*4+3] = (int8_t)fminf(fmaxf(rintf(v.w / s), -127.f), 127.f);
        }
        *(int4*)(q + (size_t)wb * 1024 + lane * 16) = *(const int4*)tmp;
    }
}

// ---------------- streaming: staged int16 h -> staged int8 hq ----------
__global__ void quant_h_kernel(const short8* __restrict__ h16s,
                               const float* __restrict__ tilescale,
                               const float* __restrict__ hslot,
                               char8* __restrict__ q, int n8) {
    const float sh = fmaxf(*hslot, 1e-8f) / QMAXF;
    const float inv = 1.0f / (32767.f * sh);   // hoisted: one exact fdiv/thread
    int stride = gridDim.x * blockDim.x;
    for (int i = blockIdx.x * blockDim.x + threadIdx.x; i < n8; i += stride) {
        const int blk = i >> 7;            // (i*8)/1024
        const int rb = blk >> 6, kc = blk & 63;
        const int tile = (rb >> 3) * 32 + (kc >> 1);
        const float f = tilescale[tile] * inv;
        short8 v = h16s[i];
        char8 o;
#pragma unroll
        for (int j = 0; j < 8; j++)
            o[j] = (int8_t)fminf(fmaxf(rintf((float)v[j] * f), -127.f), 127.f);
        q[i] = o;
    }
}

// ---------------- int8 GEMM, LDS-staged double-buffer K-loop --------------
#define EPI_G1_STORE_I16 0   // g=gelu(..); tilemax; store staged int16
#define EPI_G1_MAXONLY   1   // g=gelu(..); atomicMax only (fallback)
#define EPI_G1_QUANT     2   // g=gelu(..); store staged int8 (fallback)
#define EPI_G2_OUT       3   // out = acc*s + b; store fp32 row-major

template <int EPI>
__global__ __launch_bounds__(512, 4) void gemm_i8_kernel(
    const int8_t* __restrict__ A, const int8_t* __restrict__ B,
    int N, int K,
    const float* __restrict__ slotA, const float* __restrict__ slotB,
    const float* __restrict__ bias,
    int16_t* __restrict__ h16_out,        // EPI 0 (staged layout)
    float* __restrict__ tilescale,        // EPI 0
    unsigned int* __restrict__ maxslot,   // EPI 0/1
    const float* __restrict__ hslot,      // EPI 2
    int8_t* __restrict__ q_out,           // EPI 2
    float* __restrict__ out)              // EPI 3
{
    // K-loop: two 32KB operand buffers (A 16KB + B 16KB each).
    // Epilogue: aliased as 8 x 8KB wave-private int16 transpose regions.
    __shared__ __align__(16) int8_t lds[65536];
    __shared__ float red[8];

    const int tid  = threadIdx.x;
    const int lane = tid & 63;
    const int wv   = tid >> 6;     // 0..7
    const int wm   = wv & 3;       // 64-row quarter
    const int wn   = wv >> 2;      // 128-col half

    const int bm = blockIdx.x * 256;   // M fast
    const int bn = blockIdx.y * 256;
    const int nkb = K >> 6;

    const float sAB = (fmaxf(*slotA, 1e-8f) / QMAXF) *
                      (fmaxf(*slotB, 1e-8f) / QMAXF);

    v4i acc[4][8] = {};

    const size_t rbstride = (size_t)nkb * 1024;

    // 32 x 1KB chunks per k-step; wave wv stages chunks wv*4 .. wv*4+3.
    // chunk c<16: A row-block (bm>>4)+c ; c>=16: B row-block (bn>>4)+(c-16).
    const int8_t* src[4];
#pragma unroll
    for (int j = 0; j < 4; j++) {
        const int c = wv * 4 + j;
        src[j] = (c < 16 ? A + (size_t)((bm >> 4) + c) * rbstride
                         : B + (size_t)((bn >> 4) + (c - 16)) * rbstride)
                 + lane * 16;
    }

    auto STAGE = [&](int buf, int kt) {
#pragma unroll
        for (int j = 0; j < 4; j++) {
            __builtin_amdgcn_global_load_lds(
                (const __attribute__((address_space(1))) unsigned int*)
                    (src[j] + (size_t)kt * 1024),
                (__attribute__((address_space(3))) unsigned int*)
                    (lds + buf * 32768 + (wv * 4 + j) * 1024),
                16, 0, 0);
        }
    };
    auto LOADF = [&](int buf, v4i (&af)[4], v4i (&bf)[8]) {
        const int8_t* pa = lds + buf * 32768 + (wm * 4) * 1024 + lane * 16;
        const int8_t* pb = lds + buf * 32768 + 16384 + (wn * 8) * 1024 + lane * 16;
#pragma unroll
        for (int i = 0; i < 4; i++) af[i] = *(const v4i*)(pa + i * 1024);
#pragma unroll
        for (int i = 0; i < 8; i++) bf[i] = *(const v4i*)(pb + i * 1024);
    };
    auto MFMA = [&](v4i (&af)[4], v4i (&bf)[8]) {
#pragma unroll
        for (int mi = 0; mi < 4; mi++)
#pragma unroll
            for (int ni = 0; ni < 8; ni++)
                acc[mi][ni] = __builtin_amdgcn_mfma_i32_16x16x64_i8(
                    af[mi], bf[ni], acc[mi][ni], 0, 0, 0);
    };

    // prologue: fill both buffers (8 global_load_lds in flight)
    STAGE(0, 0);
    STAGE(1, 1);

    v4i af[4], bf[8];
    for (int kt = 0; kt < nkb - 2; ++kt) {
        // steady state: 8 outstanding {kt(4, oldest), kt+1(4)} -> wait kt's
        asm volatile("s_waitcnt vmcnt(4)" ::: "memory");
        __builtin_amdgcn_s_barrier();            // buf[kt&1] fully staged
        __builtin_amdgcn_sched_barrier(0);
        LOADF(kt & 1, af, bf);
        asm volatile("s_waitcnt lgkmcnt(0)" ::: "memory");
        __builtin_amdgcn_sched_barrier(0);
        __builtin_amdgcn_s_barrier();            // all waves done reading
        __builtin_amdgcn_sched_barrier(0);
        STAGE(kt & 1, kt + 2);                   // overwrite, loads in flight
        __builtin_amdgcn_s_setprio(1);
        MFMA(af, bf);
        __builtin_amdgcn_s_setprio(0);
    }
    // tail: kt = nkb-2, nkb-1 (no further staging)
    {
        asm volatile("s_waitcnt vmcnt(4)" ::: "memory");
        __builtin_amdgcn_s_barrier();
        __builtin_amdgcn_sched_barrier(0);
        LOADF(nkb & 1, af, bf);                  // (nkb-2)&1 == nkb&1
        v4i af2[4], bf2[8];
        asm volatile("s_waitcnt vmcnt(0)" ::: "memory");
        __builtin_amdgcn_s_barrier();
        __builtin_amdgcn_sched_barrier(0);
        LOADF((nkb - 1) & 1, af2, bf2);
        __builtin_amdgcn_s_setprio(1);
        MFMA(af, bf);
        MFMA(af2, bf2);
        __builtin_amdgcn_s_setprio(0);
    }

    __syncthreads();  // drain; LDS switches to epilogue transpose use

    // ---------------- epilogue ----------------
    float sc_q = 0.f;
    if constexpr (EPI == EPI_G1_QUANT) sc_q = fmaxf(*hslot, 1e-8f) / QMAXF;
    float lmax = 0.f;

    // phase 1: dequant + bias (+ GELU); park result bits back into acc regs
#pragma unroll
    for (int mi = 0; mi < 4; mi++) {
#pragma unroll
        for (int ni = 0; ni < 8; ni++) {
            const int col = bn + wn * 128 + ni * 16 + (lane & 15);
            const float bv = bias[col];
#pragma unroll
            for (int r = 0; r < 4; r++) {
                float val = (float)acc[mi][ni][r] * sAB + bv;
                if constexpr (EPI == EPI_G2_OUT) {
                    acc[mi][ni][r] = __float_as_int(val);
                } else {
                    float g = gelu_exact(val);
                    lmax = fmaxf(lmax, fabsf(g));
                    acc[mi][ni][r] = __float_as_int(g);
                }
            }
        }
    }

    float enc = 0.f;
    if constexpr (EPI == EPI_G1_STORE_I16 || EPI == EPI_G1_MAXONLY) {
#pragma unroll
        for (int off = 32; off > 0; off >>= 1)
            lmax = fmaxf(lmax, __shfl_xor(lmax, off));
        if (lane == 0) red[wv] = lmax;
        __syncthreads();
        float m = red[0];
#pragma unroll
        for (int i = 1; i < 8; i++) m = fmaxf(m, red[i]);
        if (tid == 0) {
            if constexpr (EPI == EPI_G1_STORE_I16) {
                // per-128x128 tile scale grid, row-major [M/128][N/128]
                const int TS = N >> 7;
                const int tr = bm >> 7, tc = bn >> 7;
                tilescale[(size_t)tr * TS + tc]           = m;
                tilescale[(size_t)tr * TS + tc + 1]       = m;
                tilescale[(size_t)(tr + 1) * TS + tc]     = m;
                tilescale[(size_t)(tr + 1) * TS + tc + 1] = m;
            }
            atomicMax(maxslot, __float_as_uint(m));
        }
        enc = 32767.f / fmaxf(m, 1e-20f);
    }

    // phase 2: stores
    if constexpr (EPI == EPI_G1_STORE_I16) {
        // wave-private 8KB LDS regions (aliasing operand buffer) -> no barriers
        const int r16 = (lane >> 4) * 4;
        const int c15 = lane & 15;
        int16_t* tl = (int16_t*)lds;
#pragma unroll
        for (int half = 0; half < 2; half++) {
#pragma unroll
            for (int mi = 0; mi < 4; mi++)
#pragma unroll
                for (int nih = 0; nih < 4; nih++) {
                    const int ni = half * 4 + nih;
#pragma unroll
                    for (int r = 0; r < 4; r++) {
                        float g = __int_as_float(acc[mi][ni][r]);
                        tl[wv * 4096 + mi * 1024 + nih * 256 + (r16 + r) * 16 + c15] =
                            (int16_t)rintf(g * enc);
                    }
                }
            const int kc = (bn >> 6) + wn * 2 + half;
#pragma unroll
            for (int mi = 0; mi < 4; mi++) {
                const int rb = (bm >> 4) + wm * 4 + mi;
                int16_t* dst = h16_out + ((size_t)rb * (N >> 6) + kc) * 1024;
                const int16_t* src2 = tl + wv * 4096 + mi * 1024;
                *(int4*)(dst + lane * 8)       = *(const int4*)(src2 + lane * 8);
                *(int4*)(dst + 512 + lane * 8) = *(const int4*)(src2 + 512 + lane * 8);
            }
        }
    } else if constexpr (EPI != EPI_G1_MAXONLY) {
#pragma unroll
        for (int mi = 0; mi < 4; mi++) {
            const int row0 = bm + wm * 64 + mi * 16 + (lane >> 4) * 4;
#pragma unroll
            for (int ni = 0; ni < 8; ni++) {
                const int col = bn + wn * 128 + ni * 16 + (lane & 15);
#pragma unroll
                for (int r = 0; r < 4; r++) {
                    const int row = row0 + r;
                    float g = __int_as_float(acc[mi][ni][r]);
                    if constexpr (EPI == EPI_G2_OUT) {
                        out[(size_t)row * N + col] = g;
                    } else {  // EPI_G1_QUANT fallback: staged int8 scatter
                        float qv = fminf(fmaxf(rintf(g / sc_q), -127.f), 127.f);
                        size_t off = ((size_t)(row >> 4) * (N >> 6) + (col >> 6)) * 1024
                                   + ((col >> 4) & 3) * 256 + (row & 15) * 16 + (col & 15);
                        q_out[off] = (int8_t)qv;
                    }
                }
            }
        }
    }
}

// ---------------------------------------------------------------------------

extern "C" void kernel_launch(void* const* d_in, const int* in_sizes, int n_in,
                              void* d_out, int out_size, void* d_ws, size_t ws_size,
                              hipStream_t stream) {
    const float* x  = (const float*)d_in[0];  // (4,4096,1024)
    const float* w1 = (const float*)d_in[1];  // (4096,1024)
    const float* b1 = (const float*)d_in[2];  // (4096,)
    const float* w2 = (const float*)d_in[3];  // (1024,4096)
    const float* b2 = (const float*)d_in[4];  // (1024,)
    float* out = (float*)d_out;               // (4,4096,1024) fp32

    const int D = 1024, H = 4096;
    const int Mrows = 4 * 4096;  // 16384

    // ---- workspace layout ----
    uintptr_t ws = (uintptr_t)d_ws;
    unsigned int* slots = (unsigned int*)ws;   // [0]=|x| [1]=|w1| [2]=|w2| [3]=|h|
    const float* slotf = (const float*)ws;
    float* tiles = (float*)(ws + 256);                 // 4096 tile scales
    int8_t* xq  = (int8_t*)(ws + 256 + 65536);         // staged 16 MB
    int8_t* w1q = xq + (size_t)Mrows * D;              // staged 4 MB
    int8_t* w2q = w1q + (size_t)H * D;                 // staged 4 MB
    int8_t* hq  = w2q + (size_t)D * H;                 // staged 64 MB
    int16_t* h16 = (int16_t*)(hq + (size_t)Mrows * H); // staged 128 MB
    const size_t need_i16 =
        256 + 65536 + (size_t)Mrows * D + 2u * (size_t)H * D +
        (size_t)Mrows * H + (size_t)Mrows * H * sizeof(int16_t);  // ~216 MB
    const bool use_store = ws_size >= need_i16;  // constant per session

    // ---- scales ----
    init_slots<<<dim3(1), dim3(64), 0, stream>>>(slots);
    absmax_kernel<<<dim3(1024), dim3(256), 0, stream>>>(
        (const float4*)x, Mrows * D / 4, slots + 0);
    absmax_kernel<<<dim3(256), dim3(256), 0, stream>>>(
        (const float4*)w1, H * D / 4, slots + 1);
    absmax_kernel<<<dim3(256), dim3(256), 0, stream>>>(
        (const float4*)w2, D * H / 4, slots + 2);

    // ---- quantize + stage inputs (coalesced) ----
    quant_stage_kernel<<<dim3(1024), dim3(256), 0, stream>>>(
        x, 4, (Mrows / 16) * (D / 64), slotf + 0, xq);
    quant_stage_kernel<<<dim3(256), dim3(256), 0, stream>>>(
        w1, 4, (H / 16) * (D / 64), slotf + 1, w1q);
    quant_stage_kernel<<<dim3(256), dim3(256), 0, stream>>>(
        w2, 6, (D / 16) * (H / 64), slotf + 2, w2q);

    // ---- GEMM1: (16384x1024)·(4096x1024)^T + b1, GELU ----
    dim3 g1(Mrows / 256, H / 256);  // (64, 16), M fast
    if (use_store) {
        gemm_i8_kernel<EPI_G1_STORE_I16><<<g1, dim3(512), 0, stream>>>(
            xq, w1q, H, D, slotf + 0, slotf + 1, b1,
            h16, tiles, slots + 3, nullptr, nullptr, nullptr);
        quant_h_kernel<<<dim3(2048), dim3(256), 0, stream>>>(
            (const short8*)h16, tiles, slotf + 3, (char8*)hq, Mrows * H / 8);
    } else {
        gemm_i8_kernel<EPI_G1_MAXONLY><<<g1, dim3(512), 0, stream>>>(
            xq, w1q, H, D, slotf + 0, slotf + 1, b1,
            nullptr, nullptr, slots + 3, nullptr, nullptr, nullptr);
        gemm_i8_kernel<EPI_G1_QUANT><<<g1, dim3(512), 0, stream>>>(
            xq, w1q, H, D, slotf + 0, slotf + 1, b1,
            nullptr, nullptr, nullptr, slotf + 3, hq, nullptr);
    }

    // ---- GEMM2: (16384x4096)·(1024x4096)^T + b2 -> out ----
    dim3 g2(Mrows / 256, D / 256);  // (64, 4), M fast
    gemm_i8_kernel<EPI_G2_OUT><<<g2, dim3(512), 0, stream>>>(
        hq, w2q, D, H, slotf + 3, slotf + 2, b2,
        nullptr, nullptr, nullptr, nullptr, nullptr, out);
}

// Round 2
// 458.705 us; speedup vs baseline: 4.0826x; 4.0826x over previous
//
#include <hip/hip_runtime.h>
#include <hip/hip_bf16.h>
#include <math.h>
#include <stdint.h>

// ---------------------------------------------------------------------------
// HMQ MLP: fake-quant(int8) GEMM1 + bias + exact GELU -> fake-quant -> GEMM2
// int8 MFMA (mfma_i32_16x16x64_i8), exact int32 accumulation.
// R8: R7's LDS-staged double-buffer K-loop (counted vmcnt, raw s_barrier,
// setprio around MFMA) with the spill fixed: __launch_bounds__(512,2).
// R7's (512,4) forced a 128-VGPR cap on a ~220-reg kernel -> accumulator
// spill to scratch (FETCH 1.45GB, WRITE 2.8GB, MfmaUtil 3%). At (512,2)
// the 256-VGPR cap fits acc(128) + operands(48) + addressing with zero
// spill; 2 waves/SIMD, 1 block/CU, LDS 64KB operand double-buffer.
//   - block 256x256, 8 waves (wave tile 64x128 -> epilogue unchanged)
//   - K-step 64: A(16KB)+B(16KB) staged via global_load_lds (1KB/instr,
//     linear dest; int8 staged layout == MFMA fragment layout, so LDS reads
//     are contiguous 1KB ds_read_b128: swizzle-free, conflict-free)
//   - 2-deep prefetch, s_waitcnt vmcnt(4) in steady state (never drain)
// Epilogue LDS transpose aliases the operand buffer (64 KB total).
// ---------------------------------------------------------------------------

typedef int    v4i    __attribute__((ext_vector_type(4)));
typedef short  short8 __attribute__((ext_vector_type(8)));
typedef int8_t char8  __attribute__((ext_vector_type(8)));

#define QMAXF 127.0f

// branch-free GELU: erf via Abramowitz-Stegun 7.1.26, |eps|<2e-7
__device__ __forceinline__ float gelu_exact(float v) {
    float z = fabsf(v) * 0.70710678118654752440f;
    float t = __builtin_amdgcn_rcpf(fmaf(0.3275911f, z, 1.0f));
    float p = fmaf(fmaf(fmaf(fmaf(1.061405429f, t, -1.453152027f), t,
                             1.421413741f), t, -0.284496736f), t,
                   0.254829592f) * t;
    float e = __expf(-z * z);
    float erfz = fmaf(-p, e, 1.0f);
    float erfv = v < 0.f ? -erfz : erfz;
    return 0.5f * v * (1.0f + erfv);
}

// ---------------- init: zero the scale slots ----------------
__global__ void init_slots(unsigned int* slots) {
    if (threadIdx.x < 8) slots[threadIdx.x] = 0u;
}

// ---------------- absmax reduction (fp32, float4) ----------------
__global__ void absmax_kernel(const float4* __restrict__ t, int n4,
                              unsigned int* __restrict__ slot) {
    float m = 0.f;
    int stride = gridDim.x * blockDim.x;
    for (int i = blockIdx.x * blockDim.x + threadIdx.x; i < n4; i += stride) {
        float4 v = t[i];
        m = fmaxf(m, fmaxf(fmaxf(fabsf(v.x), fabsf(v.y)),
                           fmaxf(fabsf(v.z), fabsf(v.w))));
    }
#pragma unroll
    for (int off = 32; off > 0; off >>= 1)
        m = fmaxf(m, __shfl_xor(m, off));
    if ((threadIdx.x & 63) == 0)
        atomicMax(slot, __float_as_uint(m));  // vals >= 0: uint order == float order
}

// ---------------- quantize fp32 -> staged int8, coalesced ----------------
// One wave per 1KB-dest block (16 rows x 64 k). Reads 4x 1KB instrs covering
// 4 full 256B row-segments each (coalesced); transposes via wave-private LDS;
// writes 1KB contiguous.
__global__ void quant_stage_kernel(const float* __restrict__ x, int kshift,
                                   int nblocks, const float* __restrict__ slot,
                                   int8_t* __restrict__ q) {
    __shared__ float qt[4][1088];  // per wave: 16 rows x 68 (pad 4) floats
    const float s = fmaxf(*slot, 1e-8f) / QMAXF;
    const int lane = threadIdx.x & 63;
    const int wv   = threadIdx.x >> 6;
    const int wave0 = (blockIdx.x * blockDim.x + threadIdx.x) >> 6;
    const int nwaves = (gridDim.x * blockDim.x) >> 6;
    const int nkb = 1 << kshift;  // K/64
    const int K = 64 << kshift;
    float* tw = &qt[wv][0];
    for (int wb = wave0; wb < nblocks; wb += nwaves) {
        const int rb = wb >> kshift;
        const int kc = wb & (nkb - 1);
        // coalesced read: instr j covers rows rb*16+j*4..+3, 256B per row
#pragma unroll
        for (int j = 0; j < 4; j++) {
            const int row = rb * 16 + j * 4 + (lane >> 4);
            float4 v = *(const float4*)(x + (size_t)row * K + kc * 64 + (lane & 15) * 4);
            *(float4*)(tw + (j * 4 + (lane >> 4)) * 68 + (lane & 15) * 4) = v;
        }
        // fragment gather: lane -> row15 = lane&15, k-chunk = (lane>>4)*16
        int8_t tmp[16];
#pragma unroll
        for (int t = 0; t < 4; t++) {
            float4 v = *(const float4*)(tw + (lane & 15) * 68 + (lane >> 4) * 16 + t * 4);
            tmp[t*4+0] = (int8_t)fminf(fmaxf(rintf(v.x / s), -127.f), 127.f);
            tmp[t*4+1] = (int8_t)fminf(fmaxf(rintf(v.y / s), -127.f), 127.f);
            tmp[t*4+2] = (int8_t)fminf(fmaxf(rintf(v.z / s), -127.f), 127.f);
            tmp[t*4+3] = (int8_t)fminf(fmaxf(rintf(v.w / s), -127.f), 127.f);
        }
        *(int4*)(q + (size_t)wb * 1024 + lane * 16) = *(const int4*)tmp;
    }
}

// ---------------- streaming: staged int16 h -> staged int8 hq ----------
__global__ void quant_h_kernel(const short8* __restrict__ h16s,
                               const float* __restrict__ tilescale,
                               const float* __restrict__ hslot,
                               char8* __restrict__ q, int n8) {
    const float sh = fmaxf(*hslot, 1e-8f) / QMAXF;
    const float inv = 1.0f / (32767.f * sh);   // hoisted: one exact fdiv/thread
    int stride = gridDim.x * blockDim.x;
    for (int i = blockIdx.x * blockDim.x + threadIdx.x; i < n8; i += stride) {
        const int blk = i >> 7;            // (i*8)/1024
        const int rb = blk >> 6, kc = blk & 63;
        const int tile = (rb >> 3) * 32 + (kc >> 1);
        const float f = tilescale[tile] * inv;
        short8 v = h16s[i];
        char8 o;
#pragma unroll
        for (int j = 0; j < 8; j++)
            o[j] = (int8_t)fminf(fmaxf(rintf((float)v[j] * f), -127.f), 127.f);
        q[i] = o;
    }
}

// ---------------- int8 GEMM, LDS-staged double-buffer K-loop --------------
#define EPI_G1_STORE_I16 0   // g=gelu(..); tilemax; store staged int16
#define EPI_G1_MAXONLY   1   // g=gelu(..); atomicMax only (fallback)
#define EPI_G1_QUANT     2   // g=gelu(..); store staged int8 (fallback)
#define EPI_G2_OUT       3   // out = acc*s + b; store fp32 row-major

template <int EPI>
__global__ __launch_bounds__(512, 2) void gemm_i8_kernel(
    const int8_t* __restrict__ A, const int8_t* __restrict__ B,
    int N, int K,
    const float* __restrict__ slotA, const float* __restrict__ slotB,
    const float* __restrict__ bias,
    int16_t* __restrict__ h16_out,        // EPI 0 (staged layout)
    float* __restrict__ tilescale,        // EPI 0
    unsigned int* __restrict__ maxslot,   // EPI 0/1
    const float* __restrict__ hslot,      // EPI 2
    int8_t* __restrict__ q_out,           // EPI 2
    float* __restrict__ out)              // EPI 3
{
    // K-loop: two 32KB operand buffers (A 16KB + B 16KB each).
    // Epilogue: aliased as 8 x 8KB wave-private int16 transpose regions.
    __shared__ __align__(16) int8_t lds[65536];
    __shared__ float red[8];

    const int tid  = threadIdx.x;
    const int lane = tid & 63;
    const int wv   = tid >> 6;     // 0..7
    const int wm   = wv & 3;       // 64-row quarter
    const int wn   = wv >> 2;      // 128-col half

    const int bm = blockIdx.x * 256;   // M fast
    const int bn = blockIdx.y * 256;
    const int nkb = K >> 6;

    const float sAB = (fmaxf(*slotA, 1e-8f) / QMAXF) *
                      (fmaxf(*slotB, 1e-8f) / QMAXF);

    v4i acc[4][8] = {};

    const size_t rbstride = (size_t)nkb * 1024;

    // 32 x 1KB chunks per k-step; wave wv stages chunks wv*4 .. wv*4+3.
    // chunk c<16: A row-block (bm>>4)+c ; c>=16: B row-block (bn>>4)+(c-16).
    const int8_t* src[4];
#pragma unroll
    for (int j = 0; j < 4; j++) {
        const int c = wv * 4 + j;
        src[j] = (c < 16 ? A + (size_t)((bm >> 4) + c) * rbstride
                         : B + (size_t)((bn >> 4) + (c - 16)) * rbstride)
                 + lane * 16;
    }

    auto STAGE = [&](int buf, int kt) {
#pragma unroll
        for (int j = 0; j < 4; j++) {
            __builtin_amdgcn_global_load_lds(
                (const __attribute__((address_space(1))) unsigned int*)
                    (src[j] + (size_t)kt * 1024),
                (__attribute__((address_space(3))) unsigned int*)
                    (lds + buf * 32768 + (wv * 4 + j) * 1024),
                16, 0, 0);
        }
    };
    auto LOADF = [&](int buf, v4i (&af)[4], v4i (&bf)[8]) {
        const int8_t* pa = lds + buf * 32768 + (wm * 4) * 1024 + lane * 16;
        const int8_t* pb = lds + buf * 32768 + 16384 + (wn * 8) * 1024 + lane * 16;
#pragma unroll
        for (int i = 0; i < 4; i++) af[i] = *(const v4i*)(pa + i * 1024);
#pragma unroll
        for (int i = 0; i < 8; i++) bf[i] = *(const v4i*)(pb + i * 1024);
    };
    auto MFMA = [&](v4i (&af)[4], v4i (&bf)[8]) {
#pragma unroll
        for (int mi = 0; mi < 4; mi++)
#pragma unroll
            for (int ni = 0; ni < 8; ni++)
                acc[mi][ni] = __builtin_amdgcn_mfma_i32_16x16x64_i8(
                    af[mi], bf[ni], acc[mi][ni], 0, 0, 0);
    };

    // prologue: fill both buffers (8 global_load_lds in flight)
    STAGE(0, 0);
    STAGE(1, 1);

    v4i af[4], bf[8];
    for (int kt = 0; kt < nkb - 2; ++kt) {
        // steady state: 8 outstanding {kt(4, oldest), kt+1(4)} -> wait kt's
        asm volatile("s_waitcnt vmcnt(4)" ::: "memory");
        __builtin_amdgcn_s_barrier();            // buf[kt&1] fully staged
        __builtin_amdgcn_sched_barrier(0);
        LOADF(kt & 1, af, bf);
        asm volatile("s_waitcnt lgkmcnt(0)" ::: "memory");
        __builtin_amdgcn_sched_barrier(0);
        __builtin_amdgcn_s_barrier();            // all waves done reading
        __builtin_amdgcn_sched_barrier(0);
        STAGE(kt & 1, kt + 2);                   // overwrite, loads in flight
        __builtin_amdgcn_s_setprio(1);
        MFMA(af, bf);
        __builtin_amdgcn_s_setprio(0);
    }
    // tail: kt = nkb-2, nkb-1 (no further staging)
    {
        asm volatile("s_waitcnt vmcnt(4)" ::: "memory");
        __builtin_amdgcn_s_barrier();
        __builtin_amdgcn_sched_barrier(0);
        LOADF(nkb & 1, af, bf);                  // (nkb-2)&1 == nkb&1
        v4i af2[4], bf2[8];
        asm volatile("s_waitcnt vmcnt(0)" ::: "memory");
        __builtin_amdgcn_s_barrier();
        __builtin_amdgcn_sched_barrier(0);
        LOADF((nkb - 1) & 1, af2, bf2);
        __builtin_amdgcn_s_setprio(1);
        MFMA(af, bf);
        MFMA(af2, bf2);
        __builtin_amdgcn_s_setprio(0);
    }

    __syncthreads();  // drain; LDS switches to epilogue transpose use

    // ---------------- epilogue ----------------
    float sc_q = 0.f;
    if constexpr (EPI == EPI_G1_QUANT) sc_q = fmaxf(*hslot, 1e-8f) / QMAXF;
    float lmax = 0.f;

    // phase 1: dequant + bias (+ GELU); park result bits back into acc regs
#pragma unroll
    for (int mi = 0; mi < 4; mi++) {
#pragma unroll
        for (int ni = 0; ni < 8; ni++) {
            const int col = bn + wn * 128 + ni * 16 + (lane & 15);
            const float bv = bias[col];
#pragma unroll
            for (int r = 0; r < 4; r++) {
                float val = (float)acc[mi][ni][r] * sAB + bv;
                if constexpr (EPI == EPI_G2_OUT) {
                    acc[mi][ni][r] = __float_as_int(val);
                } else {
                    float g = gelu_exact(val);
                    lmax = fmaxf(lmax, fabsf(g));
                    acc[mi][ni][r] = __float_as_int(g);
                }
            }
        }
    }

    float enc = 0.f;
    if constexpr (EPI == EPI_G1_STORE_I16 || EPI == EPI_G1_MAXONLY) {
#pragma unroll
        for (int off = 32; off > 0; off >>= 1)
            lmax = fmaxf(lmax, __shfl_xor(lmax, off));
        if (lane == 0) red[wv] = lmax;
        __syncthreads();
        float m = red[0];
#pragma unroll
        for (int i = 1; i < 8; i++) m = fmaxf(m, red[i]);
        if (tid == 0) {
            if constexpr (EPI == EPI_G1_STORE_I16) {
                // per-128x128 tile scale grid, row-major [M/128][N/128]
                const int TS = N >> 7;
                const int tr = bm >> 7, tc = bn >> 7;
                tilescale[(size_t)tr * TS + tc]           = m;
                tilescale[(size_t)tr * TS + tc + 1]       = m;
                tilescale[(size_t)(tr + 1) * TS + tc]     = m;
                tilescale[(size_t)(tr + 1) * TS + tc + 1] = m;
            }
            atomicMax(maxslot, __float_as_uint(m));
        }
        enc = 32767.f / fmaxf(m, 1e-20f);
    }

    // phase 2: stores
    if constexpr (EPI == EPI_G1_STORE_I16) {
        // wave-private 8KB LDS regions (aliasing operand buffer) -> no barriers
        const int r16 = (lane >> 4) * 4;
        const int c15 = lane & 15;
        int16_t* tl = (int16_t*)lds;
#pragma unroll
        for (int half = 0; half < 2; half++) {
#pragma unroll
            for (int mi = 0; mi < 4; mi++)
#pragma unroll
                for (int nih = 0; nih < 4; nih++) {
                    const int ni = half * 4 + nih;
#pragma unroll
                    for (int r = 0; r < 4; r++) {
                        float g = __int_as_float(acc[mi][ni][r]);
                        tl[wv * 4096 + mi * 1024 + nih * 256 + (r16 + r) * 16 + c15] =
                            (int16_t)rintf(g * enc);
                    }
                }
            const int kc = (bn >> 6) + wn * 2 + half;
#pragma unroll
            for (int mi = 0; mi < 4; mi++) {
                const int rb = (bm >> 4) + wm * 4 + mi;
                int16_t* dst = h16_out + ((size_t)rb * (N >> 6) + kc) * 1024;
                const int16_t* src2 = tl + wv * 4096 + mi * 1024;
                *(int4*)(dst + lane * 8)       = *(const int4*)(src2 + lane * 8);
                *(int4*)(dst + 512 + lane * 8) = *(const int4*)(src2 + 512 + lane * 8);
            }
        }
    } else if constexpr (EPI != EPI_G1_MAXONLY) {
#pragma unroll
        for (int mi = 0; mi < 4; mi++) {
            const int row0 = bm + wm * 64 + mi * 16 + (lane >> 4) * 4;
#pragma unroll
            for (int ni = 0; ni < 8; ni++) {
                const int col = bn + wn * 128 + ni * 16 + (lane & 15);
#pragma unroll
                for (int r = 0; r < 4; r++) {
                    const int row = row0 + r;
                    float g = __int_as_float(acc[mi][ni][r]);
                    if constexpr (EPI == EPI_G2_OUT) {
                        out[(size_t)row * N + col] = g;
                    } else {  // EPI_G1_QUANT fallback: staged int8 scatter
                        float qv = fminf(fmaxf(rintf(g / sc_q), -127.f), 127.f);
                        size_t off = ((size_t)(row >> 4) * (N >> 6) + (col >> 6)) * 1024
                                   + ((col >> 4) & 3) * 256 + (row & 15) * 16 + (col & 15);
                        q_out[off] = (int8_t)qv;
                    }
                }
            }
        }
    }
}

// ---------------------------------------------------------------------------

extern "C" void kernel_launch(void* const* d_in, const int* in_sizes, int n_in,
                              void* d_out, int out_size, void* d_ws, size_t ws_size,
                              hipStream_t stream) {
    const float* x  = (const float*)d_in[0];  // (4,4096,1024)
    const float* w1 = (const float*)d_in[1];  // (4096,1024)
    const float* b1 = (const float*)d_in[2];  // (4096,)
    const float* w2 = (const float*)d_in[3];  // (1024,4096)
    const float* b2 = (const float*)d_in[4];  // (1024,)
    float* out = (float*)d_out;               // (4,4096,1024) fp32

    const int D = 1024, H = 4096;
    const int Mrows = 4 * 4096;  // 16384

    // ---- workspace layout ----
    uintptr_t ws = (uintptr_t)d_ws;
    unsigned int* slots = (unsigned int*)ws;   // [0]=|x| [1]=|w1| [2]=|w2| [3]=|h|
    const float* slotf = (const float*)ws;
    float* tiles = (float*)(ws + 256);                 // 4096 tile scales
    int8_t* xq  = (int8_t*)(ws + 256 + 65536);         // staged 16 MB
    int8_t* w1q = xq + (size_t)Mrows * D;              // staged 4 MB
    int8_t* w2q = w1q + (size_t)H * D;                 // staged 4 MB
    int8_t* hq  = w2q + (size_t)D * H;                 // staged 64 MB
    int16_t* h16 = (int16_t*)(hq + (size_t)Mrows * H); // staged 128 MB
    const size_t need_i16 =
        256 + 65536 + (size_t)Mrows * D + 2u * (size_t)H * D +
        (size_t)Mrows * H + (size_t)Mrows * H * sizeof(int16_t);  // ~216 MB
    const bool use_store = ws_size >= need_i16;  // constant per session

    // ---- scales ----
    init_slots<<<dim3(1), dim3(64), 0, stream>>>(slots);
    absmax_kernel<<<dim3(1024), dim3(256), 0, stream>>>(
        (const float4*)x, Mrows * D / 4, slots + 0);
    absmax_kernel<<<dim3(256), dim3(256), 0, stream>>>(
        (const float4*)w1, H * D / 4, slots + 1);
    absmax_kernel<<<dim3(256), dim3(256), 0, stream>>>(
        (const float4*)w2, D * H / 4, slots + 2);

    // ---- quantize + stage inputs (coalesced) ----
    quant_stage_kernel<<<dim3(1024), dim3(256), 0, stream>>>(
        x, 4, (Mrows / 16) * (D / 64), slotf + 0, xq);
    quant_stage_kernel<<<dim3(256), dim3(256), 0, stream>>>(
        w1, 4, (H / 16) * (D / 64), slotf + 1, w1q);
    quant_stage_kernel<<<dim3(256), dim3(256), 0, stream>>>(
        w2, 6, (D / 16) * (H / 64), slotf + 2, w2q);

    // ---- GEMM1: (16384x1024)·(4096x1024)^T + b1, GELU ----
    dim3 g1(Mrows / 256, H / 256);  // (64, 16), M fast
    if (use_store) {
        gemm_i8_kernel<EPI_G1_STORE_I16><<<g1, dim3(512), 0, stream>>>(
            xq, w1q, H, D, slotf + 0, slotf + 1, b1,
            h16, tiles, slots + 3, nullptr, nullptr, nullptr);
        quant_h_kernel<<<dim3(2048), dim3(256), 0, stream>>>(
            (const short8*)h16, tiles, slotf + 3, (char8*)hq, Mrows * H / 8);
    } else {
        gemm_i8_kernel<EPI_G1_MAXONLY><<<g1, dim3(512), 0, stream>>>(
            xq, w1q, H, D, slotf + 0, slotf + 1, b1,
            nullptr, nullptr, slots + 3, nullptr, nullptr, nullptr);
        gemm_i8_kernel<EPI_G1_QUANT><<<g1, dim3(512), 0, stream>>>(
            xq, w1q, H, D, slotf + 0, slotf + 1, b1,
            nullptr, nullptr, nullptr, slotf + 3, hq, nullptr);
    }

    // ---- GEMM2: (16384x4096)·(1024x4096)^T + b2 -> out ----
    dim3 g2(Mrows / 256, D / 256);  // (64, 4), M fast
    gemm_i8_kernel<EPI_G2_OUT><<<g2, dim3(512), 0, stream>>>(
        hq, w2q, D, H, slotf + 3, slotf + 2, b2,
        nullptr, nullptr, nullptr, nullptr, nullptr, out);
}